// Round 1
// baseline (916.082 us; speedup 1.0000x reference)
//
#include <hip/hip_runtime.h>
#include <math.h>

#define BB 2
#define CC 64
#define NN 16384
#define DD 3
#define KK 128
#define EE 262144
#define GG 3
#define PP 64            // n-chunks for spectral-forward partials
#define LL (NN/PP)       // 256 n per chunk

// ---- workspace layout (float elements) ----
constexpr size_t OFF_XT   = 0;                                  // xT[b][n][i]
constexpr size_t OFF_PC   = OFF_XT   + (size_t)BB*NN*CC;        // partial A_c
constexpr size_t OFF_PS   = OFF_PC   + (size_t)BB*PP*CC*KK;     // partial A_s
constexpr size_t OFF_AC   = OFF_PS   + (size_t)BB*PP*CC*KK;     // A_c[b][i][k]
constexpr size_t OFF_AS   = OFF_AC   + (size_t)BB*CC*KK;
constexpr size_t OFF_FTC  = OFF_AS   + (size_t)BB*CC*KK;        // 2*f_c[b][k][o]
constexpr size_t OFF_FTS  = OFF_FTC  + (size_t)BB*KK*CC;        // 2*f_s[b][k][o]
constexpr size_t OFF_F0   = OFF_FTS  + (size_t)BB*KK*CC;        // f0[b][o]
constexpr size_t OFF_X0   = OFF_F0   + (size_t)BB*CC;           // x0[b][i]   (zeroed)
constexpr size_t OFF_CNT  = OFF_X0   + (size_t)BB*CC;           // int counts (zeroed)
constexpr size_t OFF_OFFS = OFF_CNT  + (size_t)BB*NN;           // int offsets
constexpr size_t OFF_CUR  = OFF_OFFS + (size_t)BB*NN;           // int cursor
constexpr size_t OFF_BIN  = OFF_CUR  + (size_t)BB*NN;           // int2 binlist[b][E]
constexpr size_t OFF_GRT  = OFF_BIN  + (size_t)BB*EE*2;         // gradfT[b][g][n]
constexpr size_t OFF_H    = OFF_GRT  + (size_t)BB*192*NN;       // h[b][i][n]
constexpr size_t OFF_WT   = OFF_H    + (size_t)BB*CC*NN;        // W^T  [j][o]
constexpr size_t OFF_WXT  = OFF_WT   + (size_t)CC*CC;           // wx^T [j][i]
constexpr size_t OFF_W2T  = OFF_WXT  + (size_t)CC*CC;           // w2^T [i][o]
constexpr size_t OFF_GWT  = OFF_W2T  + (size_t)CC*CC;           // gw^T [g][o]
constexpr size_t OFF_GWXT = OFF_GWT  + (size_t)CC*CC*DD;        // geo_wx^T [g][i]

// ---- small transposes ----
__global__ void k_prep(const float* __restrict__ W, const float* __restrict__ gw,
                       const float* __restrict__ geo_wx, const float* __restrict__ wx,
                       const float* __restrict__ w2,
                       float* WT, float* wxT, float* w2T, float* gwT, float* gwxT) {
    int idx = blockIdx.x*256 + threadIdx.x;
    if (idx < CC*CC) { int j = idx>>6, o = idx&63; WT[idx]  = W[o*CC+j];  }
    if (idx < CC*CC) { int j = idx>>6, i = idx&63; wxT[idx] = wx[i*CC+j]; }
    if (idx < CC*CC) { int i = idx>>6, o = idx&63; w2T[idx] = w2[o*CC+i]; }
    if (idx < CC*CC*DD) { int g = idx>>6, o = idx&63; gwT[idx] = gw[o*(CC*DD)+g]; }
    if (idx < GG*CC) { int g = idx>>6, i = idx&63; gwxT[idx] = geo_wx[i*GG+g]; }
}

// ---- transpose x -> xT[b][n][i], plus x0 partials ----
__global__ void __launch_bounds__(256) k_xt(const float* __restrict__ x,
                                            const float* __restrict__ nwt,
                                            float* __restrict__ xT, float* __restrict__ x0) {
    int blk = blockIdx.x;
    int b = blk / (NN/64);
    int n0 = (blk % (NN/64)) * 64;
    __shared__ float tile[64][65];
    __shared__ float nwv[64];
    int tid = threadIdx.x;
    int c = tid & 63, r4 = tid >> 6;
    for (int rr = 0; rr < 16; rr++) {
        int i = r4*16 + rr;
        tile[i][c] = x[((size_t)b*CC + i)*NN + n0 + c];
    }
    if (tid < 64) nwv[tid] = nwt[b*NN + n0 + tid];
    __syncthreads();
    for (int rr = 0; rr < 16; rr++) {
        int nn = r4*16 + rr;
        xT[((size_t)b*NN + n0 + nn)*CC + c] = tile[c][nn];
    }
    // x0[b][i] += sum_n x[b][i][n]*nw[n]
    int i = tid >> 2, q = tid & 3;
    float s = 0.f;
    for (int j = 0; j < 16; j++) { int nn = q*16 + j; s += tile[i][nn] * nwv[nn]; }
    atomicAdd(&x0[b*CC + i], s);
}

// ---- spectral forward partials: A_c/A_s[b][i][k] over n-chunks ----
__global__ void __launch_bounds__(256) k_a(const float* __restrict__ xT,
                                           const float* __restrict__ nodes,
                                           const float* __restrict__ nwt,
                                           const float* __restrict__ modes,
                                           float* __restrict__ pc, float* __restrict__ ps) {
    int bc = blockIdx.x;
    int b = bc / PP, chunk = bc % PP;
    int tid = threadIdx.x;
    int lane = tid & 63;
    int w = tid >> 6;
    int khalf = w & 1;
    int ig = blockIdx.y*2 + (w >> 1);          // 0..3, 16 i's each
    int k = khalf*64 + lane;
    int i0 = __builtin_amdgcn_readfirstlane(ig * 16);
    float m0 = modes[k*3+0], m1 = modes[k*3+1], m2 = modes[k*3+2];
    float ac[16], as[16];
#pragma unroll
    for (int j = 0; j < 16; j++) { ac[j]=0.f; as[j]=0.f; }
    int nbase = chunk*LL;
    for (int t = 0; t < LL; t++) {
        int n = nbase + t;
        float nd0 = nodes[(b*NN+n)*3+0], nd1 = nodes[(b*NN+n)*3+1], nd2 = nodes[(b*NN+n)*3+2];
        float nw = nwt[b*NN+n];
        float tt = nd0*m0 + nd1*m1 + nd2*m2;
        float cv = __cosf(tt) * nw, sv = __sinf(tt) * nw;
        const float* __restrict__ xrow = &xT[((size_t)b*NN+n)*CC + i0];
#pragma unroll
        for (int j = 0; j < 16; j++) {
            float xv = xrow[j];
            ac[j] = fmaf(xv, cv, ac[j]);
            as[j] = fmaf(xv, sv, as[j]);
        }
    }
    int base = (b*PP + chunk)*CC;
#pragma unroll
    for (int j = 0; j < 16; j++) {
        pc[(size_t)(base + i0 + j)*KK + k] = ac[j];
        ps[(size_t)(base + i0 + j)*KK + k] = as[j];
    }
}

__global__ void k_ared(const float* __restrict__ pc, const float* __restrict__ ps,
                       float* __restrict__ Ac, float* __restrict__ As) {
    int idx = blockIdx.x*256 + threadIdx.x;      // over BB*CC*KK
    if (idx >= BB*CC*KK) return;
    int b = idx / (CC*KK);
    int r = idx % (CC*KK);
    float sc = 0.f, ss = 0.f;
    for (int ch = 0; ch < PP; ch++) {
        size_t o = ((size_t)(b*PP + ch)*CC)*KK + r;
        sc += pc[o]; ss += ps[o];
    }
    Ac[idx] = sc; As[idx] = ss;
}

// ---- channel mix -> 2*f_c, 2*f_s in [b][k][o] layout, + f0 ----
__global__ void k_b(const float* __restrict__ Ac, const float* __restrict__ As,
                    const float* __restrict__ wc, const float* __restrict__ wsw,
                    const float* __restrict__ w0, const float* __restrict__ x0,
                    float* __restrict__ fTc, float* __restrict__ fTs, float* __restrict__ f0) {
    int b = blockIdx.x / CC, o = blockIdx.x % CC;
    int k = threadIdx.x;                         // 128 threads
    float fc = 0.f, fs = 0.f;
    for (int i = 0; i < CC; i++) {
        float a_c = Ac[(b*CC+i)*KK + k];
        float a_s = As[(b*CC+i)*KK + k];
        float wcc = wc[((size_t)(i*CC+o))*KK + k];
        float wss = wsw[((size_t)(i*CC+o))*KK + k];
        // f_c = sum_i A_c*wc + A_s*ws ;  f_s = sum_i A_c*ws - A_s*wc
        fc += a_c*wcc + a_s*wss;
        fs += a_c*wss - a_s*wcc;
    }
    fTc[(b*KK+k)*CC + o] = 2.f*fc;
    fTs[(b*KK+k)*CC + o] = 2.f*fs;
    if (threadIdx.x == 0) {
        float acc = 0.f;
        for (int i = 0; i < CC; i++) acc += x0[b*CC+i]*w0[i*CC+o];
        f0[b*CC+o] = acc;
    }
}

// ---- edge binning ----
__global__ void k_count(const int* __restrict__ edges, int* __restrict__ counts) {
    int idx = blockIdx.x*256 + threadIdx.x;
    if (idx >= BB*EE) return;
    int tgt = edges[(size_t)idx*2 + 0];
    int b = idx / EE;
    atomicAdd(&counts[b*NN + tgt], 1);
}

__global__ void __launch_bounds__(1024) k_scan(const int* __restrict__ counts,
                                               int* __restrict__ offsets, int* __restrict__ cursor) {
    __shared__ int part[1024];
    int b = blockIdx.x;
    int tid = threadIdx.x;
    int base = tid*16;
    int loc[16]; int s = 0;
    for (int j = 0; j < 16; j++) { loc[j] = counts[b*NN + base + j]; s += loc[j]; }
    part[tid] = s;
    __syncthreads();
    for (int off = 1; off < 1024; off <<= 1) {
        int v = (tid >= off) ? part[tid-off] : 0;
        __syncthreads();
        part[tid] += v;
        __syncthreads();
    }
    int excl = part[tid] - s;
    for (int j = 0; j < 16; j++) {
        offsets[b*NN+base+j] = excl;
        cursor[b*NN+base+j]  = excl;
        excl += loc[j];
    }
}

__global__ void k_fill(const int* __restrict__ edges, int* __restrict__ cursor,
                       int2* __restrict__ binlist) {
    int idx = blockIdx.x*256 + threadIdx.x;
    if (idx >= BB*EE) return;
    int b = idx / EE, e = idx % EE;
    int tgt = edges[(size_t)idx*2+0];
    int src = edges[(size_t)idx*2+1];
    int pos = atomicAdd(&cursor[b*NN+tgt], 1);
    binlist[(size_t)b*EE + pos] = make_int2(src, e);
}

// ---- per-node edge accumulate -> gradfT[b][g][n] (atomics-free) ----
__global__ void __launch_bounds__(256) k_edge(const float* __restrict__ xT,
                                              const int* __restrict__ offsets,
                                              const int* __restrict__ counts,
                                              const int2* __restrict__ binlist,
                                              const float* __restrict__ egw,
                                              float* __restrict__ gradfT) {
    int blk = blockIdx.x;
    int b = blk / (NN/64);
    int n0 = (blk % (NN/64)) * 64;
    int tid = threadIdx.x;
    int lane = tid & 63;
    int w = tid >> 6;
    __shared__ float gl[64][193];    // [node_local][g], stride 193 -> 2-way banks
    for (int r = 0; r < 16; r++) {
        int nl = w*16 + r;
        int n = __builtin_amdgcn_readfirstlane(n0 + nl);
        float xtgt = xT[((size_t)b*NN+n)*CC + lane];
        float a0 = 0.f, a1 = 0.f, a2 = 0.f;
        int st  = offsets[b*NN+n];
        int cnt = counts[b*NN+n];
        for (int j = 0; j < cnt; j++) {
            int2 en = binlist[(size_t)b*EE + st + j];
            float xs = xT[((size_t)b*NN+en.x)*CC + lane];
            float d = xs - xtgt;
            const float* __restrict__ ew = &egw[((size_t)b*EE+en.y)*3];
            a0 = fmaf(d, ew[0], a0);
            a1 = fmaf(d, ew[1], a1);
            a2 = fmaf(d, ew[2], a2);
        }
        gl[nl][lane*3+0] = a0;
        gl[nl][lane*3+1] = a1;
        gl[nl][lane*3+2] = a2;
    }
    __syncthreads();
    for (int gg = 0; gg < 48; gg++) {
        int g = w*48 + gg;
        gradfT[((size_t)b*192+g)*NN + n0 + lane] = gl[lane][g];
    }
}

// ---- h[b][i][n] = softsign(geo_wx@geo) * (wx@x) ----
__global__ void __launch_bounds__(64) k_h(const float* __restrict__ x,
                                          const float* __restrict__ geo,
                                          const float* __restrict__ wxT,
                                          const float* __restrict__ gwxT,
                                          float* __restrict__ hbuf) {
    int blk = blockIdx.x;
    int b = blk / (NN/64);
    int n0 = (blk % (NN/64)) * 64;
    int i0 = blockIdx.y * 32;
    int lane = threadIdx.x;
    int n = n0 + lane;
    float xw[32];
#pragma unroll
    for (int ii = 0; ii < 32; ii++) xw[ii] = 0.f;
    for (int j = 0; j < CC; j++) {
        float xv = x[((size_t)b*CC+j)*NN + n];
        const float* __restrict__ wr = &wxT[j*CC + i0];
#pragma unroll
        for (int ii = 0; ii < 32; ii++) xw[ii] = fmaf(wr[ii], xv, xw[ii]);
    }
    float g0 = geo[((size_t)b*GG+0)*NN + n];
    float g1 = geo[((size_t)b*GG+1)*NN + n];
    float g2 = geo[((size_t)b*GG+2)*NN + n];
#pragma unroll
    for (int ii = 0; ii < 32; ii++) {
        int i = i0 + ii;
        float t = gwxT[0*CC+i]*g0 + gwxT[1*CC+i]*g1 + gwxT[2*CC+i]*g2;
        float ssv = t / (1.f + fabsf(t));
        hbuf[((size_t)b*CC+i)*NN + n] = ssv * xw[ii];
    }
}

// ---- fused final: x1 + x2 + x3 + x4 -> exact GELU ----
__global__ void __launch_bounds__(256) k_c(const float* __restrict__ x,
                                           const float* __restrict__ nodes,
                                           const float* __restrict__ modes,
                                           const float* __restrict__ fTc,
                                           const float* __restrict__ fTs,
                                           const float* __restrict__ f0,
                                           const float* __restrict__ WT,
                                           const float* __restrict__ w2T,
                                           const float* __restrict__ gwT,
                                           const float* __restrict__ gradfT,
                                           const float* __restrict__ hbuf,
                                           float* __restrict__ out) {
    int blk = blockIdx.x;
    int b = blk / (NN/64);
    int n0 = (blk % (NN/64)) * 64;
    int tid = threadIdx.x;
    int lane = tid & 63;
    int o0 = __builtin_amdgcn_readfirstlane((tid >> 6) * 16);
    int n = n0 + lane;
    __shared__ float csc[KK*64];     // [k][n]: bank = n%32 -> 2-way (free)
    __shared__ float css[KK*64];
    // phase 0: cos/sin tile (each thread keeps its own node coords; nn == lane)
    float nd0 = nodes[((size_t)b*NN+n)*3+0];
    float nd1 = nodes[((size_t)b*NN+n)*3+1];
    float nd2 = nodes[((size_t)b*NN+n)*3+2];
    for (int r = 0; r < 32; r++) {
        int k = __builtin_amdgcn_readfirstlane(r*4 + (tid >> 6));
        float t = nd0*modes[k*3+0] + nd1*modes[k*3+1] + nd2*modes[k*3+2];
        csc[k*64+lane] = __cosf(t);
        css[k*64+lane] = __sinf(t);
    }
    __syncthreads();
    float acc[16];
    const float* __restrict__ f0p = &f0[b*CC + o0];
#pragma unroll
    for (int oo = 0; oo < 16; oo++) acc[oo] = f0p[oo];
    // x1: 2*sum_k f_c*cos - 2*sum_k f_s*sin  (f rows pre-scaled by 2)
    for (int k = 0; k < KK; k++) {
        float cv = csc[k*64 + lane];
        float sv = css[k*64 + lane];
        const float* __restrict__ fc = &fTc[(b*KK+k)*CC + o0];
        const float* __restrict__ fs = &fTs[(b*KK+k)*CC + o0];
#pragma unroll
        for (int oo = 0; oo < 16; oo++)
            acc[oo] += fc[oo]*cv - fs[oo]*sv;
    }
    // x2: W @ x
    for (int j = 0; j < CC; j++) {
        float xv = x[((size_t)b*CC+j)*NN + n];
        const float* __restrict__ wr = &WT[j*CC + o0];
#pragma unroll
        for (int oo = 0; oo < 16; oo++) acc[oo] = fmaf(wr[oo], xv, acc[oo]);
    }
    // x4: w2 @ h
    for (int i = 0; i < CC; i++) {
        float hv = hbuf[((size_t)b*CC+i)*NN + n];
        const float* __restrict__ wr = &w2T[i*CC + o0];
#pragma unroll
        for (int oo = 0; oo < 16; oo++) acc[oo] = fmaf(wr[oo], hv, acc[oo]);
    }
    // x3: gw @ gradf
    for (int g = 0; g < 192; g++) {
        float gv = gradfT[((size_t)b*192+g)*NN + n];
        const float* __restrict__ wr = &gwT[g*CC + o0];
#pragma unroll
        for (int oo = 0; oo < 16; oo++) acc[oo] = fmaf(wr[oo], gv, acc[oo]);
    }
    // exact GELU + store
#pragma unroll
    for (int oo = 0; oo < 16; oo++) {
        float v = acc[oo];
        float r = 0.5f * v * (1.f + erff(v * 0.70710678118654752f));
        out[((size_t)b*CC + o0 + oo)*NN + n] = r;
    }
}

extern "C" void kernel_launch(void* const* d_in, const int* in_sizes, int n_in,
                              void* d_out, int out_size, void* d_ws, size_t ws_size,
                              hipStream_t stream) {
    const float* x      = (const float*)d_in[0];
    const float* nodes  = (const float*)d_in[1];
    const float* nwt    = (const float*)d_in[2];
    const float* geo    = (const float*)d_in[3];
    const int*   edges  = (const int*)d_in[4];
    const float* egw    = (const float*)d_in[5];
    const float* modes  = (const float*)d_in[6];
    const float* wc     = (const float*)d_in[7];
    const float* wsw    = (const float*)d_in[8];
    const float* w0     = (const float*)d_in[9];
    const float* W      = (const float*)d_in[10];
    const float* gw     = (const float*)d_in[11];
    const float* geo_wx = (const float*)d_in[12];
    const float* wx     = (const float*)d_in[13];
    const float* w2     = (const float*)d_in[14];

    float* ws   = (float*)d_ws;
    float* xT   = ws + OFF_XT;
    float* pc   = ws + OFF_PC;
    float* ps   = ws + OFF_PS;
    float* Ac   = ws + OFF_AC;
    float* As   = ws + OFF_AS;
    float* fTc  = ws + OFF_FTC;
    float* fTs  = ws + OFF_FTS;
    float* f0   = ws + OFF_F0;
    float* x0   = ws + OFF_X0;
    int*  counts = (int*)(ws + OFF_CNT);
    int*  offs   = (int*)(ws + OFF_OFFS);
    int*  cur    = (int*)(ws + OFF_CUR);
    int2* bin    = (int2*)(ws + OFF_BIN);
    float* gradfT = ws + OFF_GRT;
    float* hbuf   = ws + OFF_H;
    float* WT   = ws + OFF_WT;
    float* wxT  = ws + OFF_WXT;
    float* w2T  = ws + OFF_W2T;
    float* gwT  = ws + OFF_GWT;
    float* gwxT = ws + OFF_GWXT;
    float* out  = (float*)d_out;

    // zero x0 + counts (adjacent in layout)
    hipMemsetAsync(x0, 0, (size_t)(BB*CC + BB*NN)*sizeof(float), stream);

    k_prep <<<48, 256, 0, stream>>>(W, gw, geo_wx, wx, w2, WT, wxT, w2T, gwT, gwxT);
    k_xt   <<<BB*(NN/64), 256, 0, stream>>>(x, nwt, xT, x0);
    k_a    <<<dim3(BB*PP, 2), 256, 0, stream>>>(xT, nodes, nwt, modes, pc, ps);
    k_ared <<<(BB*CC*KK)/256, 256, 0, stream>>>(pc, ps, Ac, As);
    k_b    <<<BB*CC, 128, 0, stream>>>(Ac, As, wc, wsw, w0, x0, fTc, fTs, f0);
    k_count<<<(BB*EE)/256, 256, 0, stream>>>(edges, counts);
    k_scan <<<BB, 1024, 0, stream>>>(counts, offs, cur);
    k_fill <<<(BB*EE)/256, 256, 0, stream>>>(edges, cur, bin);
    k_edge <<<BB*(NN/64), 256, 0, stream>>>(xT, offs, counts, bin, egw, gradfT);
    k_h    <<<dim3(BB*(NN/64), 2), 64, 0, stream>>>(x, geo, wxT, gwxT, hbuf);
    k_c    <<<BB*(NN/64), 256, 0, stream>>>(x, nodes, modes, fTc, fTs, f0, WT, w2T, gwT,
                                            gradfT, hbuf, out);
}

// Round 2
// 487.942 us; speedup vs baseline: 1.8774x; 1.8774x over previous
//
#include <hip/hip_runtime.h>
#include <math.h>

#define BB 2
#define CC 64
#define NN 16384
#define DD 3
#define KK 128
#define EE 262144
#define GG 3
#define PP 64            // n-chunks for spectral-forward partials
#define LL (NN/PP)       // 256 n per chunk

// ---- workspace layout (float elements) ----
constexpr size_t OFF_XT   = 0;                                  // xT[b][n][i]
constexpr size_t OFF_PC   = OFF_XT   + (size_t)BB*NN*CC;        // partial A_c
constexpr size_t OFF_PS   = OFF_PC   + (size_t)BB*PP*CC*KK;     // partial A_s
constexpr size_t OFF_AC   = OFF_PS   + (size_t)BB*PP*CC*KK;     // A_c[b][i][k]
constexpr size_t OFF_AS   = OFF_AC   + (size_t)BB*CC*KK;
constexpr size_t OFF_FTC  = OFF_AS   + (size_t)BB*CC*KK;        // 2*f_c[b][k][o]
constexpr size_t OFF_FTS  = OFF_FTC  + (size_t)BB*KK*CC;        // 2*f_s[b][k][o]
constexpr size_t OFF_F0   = OFF_FTS  + (size_t)BB*KK*CC;        // f0[b][o]
constexpr size_t OFF_X0   = OFF_F0   + (size_t)BB*CC;           // x0[b][i]
constexpr size_t OFF_CNT  = OFF_X0   + (size_t)BB*CC;           // int counts (zeroed)
constexpr size_t OFF_OFFS = OFF_CNT  + (size_t)BB*NN;           // int offsets
constexpr size_t OFF_CUR  = OFF_OFFS + (size_t)BB*NN;           // int cursor
constexpr size_t OFF_BIN  = OFF_CUR  + (size_t)BB*NN;           // int2 binlist[b][E]
constexpr size_t OFF_GRT  = OFF_BIN  + (size_t)BB*EE*2;         // gradfT[b][g][n]
constexpr size_t OFF_H    = OFF_GRT  + (size_t)BB*192*NN;       // h[b][i][n]
constexpr size_t OFF_WT   = OFF_H    + (size_t)BB*CC*NN;        // W^T  [j][o]
constexpr size_t OFF_WXT  = OFF_WT   + (size_t)CC*CC;           // wx^T [j][i]
constexpr size_t OFF_W2T  = OFF_WXT  + (size_t)CC*CC;           // w2^T [i][o]
constexpr size_t OFF_GWT  = OFF_W2T  + (size_t)CC*CC;           // gw^T [g][o]
constexpr size_t OFF_GWXT = OFF_GWT  + (size_t)CC*CC*DD;        // geo_wx^T [g][i]

// ---- small transposes ----
__global__ void k_prep(const float* __restrict__ W, const float* __restrict__ gw,
                       const float* __restrict__ geo_wx, const float* __restrict__ wx,
                       const float* __restrict__ w2,
                       float* WT, float* wxT, float* w2T, float* gwT, float* gwxT) {
    int idx = blockIdx.x*256 + threadIdx.x;
    if (idx < CC*CC) { int j = idx>>6, o = idx&63; WT[idx]  = W[o*CC+j];  }
    if (idx < CC*CC) { int j = idx>>6, i = idx&63; wxT[idx] = wx[i*CC+j]; }
    if (idx < CC*CC) { int i = idx>>6, o = idx&63; w2T[idx] = w2[o*CC+i]; }
    if (idx < CC*CC*DD) { int g = idx>>6, o = idx&63; gwT[idx] = gw[o*(CC*DD)+g]; }
    if (idx < GG*CC) { int g = idx>>6, i = idx&63; gwxT[idx] = geo_wx[i*GG+g]; }
}

// ---- transpose x -> xT[b][n][i] (no atomics, no reductions) ----
__global__ void __launch_bounds__(256) k_xt(const float* __restrict__ x,
                                            float* __restrict__ xT) {
    int blk = blockIdx.x;
    int b = blk / (NN/64);
    int n0 = (blk % (NN/64)) * 64;
    __shared__ float tile[64][65];
    int tid = threadIdx.x;
    int c = tid & 63, r4 = tid >> 6;
    for (int rr = 0; rr < 16; rr++) {
        int i = r4*16 + rr;
        tile[i][c] = x[((size_t)b*CC + i)*NN + n0 + c];
    }
    __syncthreads();
    for (int rr = 0; rr < 16; rr++) {
        int nn = r4*16 + rr;
        xT[((size_t)b*NN + n0 + nn)*CC + c] = tile[c][nn];
    }
}

// ---- x0[b][i] = sum_n x[b,i,n] * nw[b,n] : one block per (b,i), no atomics ----
__global__ void __launch_bounds__(256) k_x0(const float* __restrict__ x,
                                            const float* __restrict__ nwt,
                                            float* __restrict__ x0) {
    int b = blockIdx.x >> 6;
    int i = blockIdx.x & 63;
    int tid = threadIdx.x;
    const float4* __restrict__ xr = (const float4*)&x[((size_t)b*CC + i)*NN];
    const float4* __restrict__ wr = (const float4*)&nwt[(size_t)b*NN];
    float s = 0.f;
    for (int t = tid; t < NN/4; t += 256) {
        float4 xv = xr[t];
        float4 wv = wr[t];
        s += xv.x*wv.x + xv.y*wv.y + xv.z*wv.z + xv.w*wv.w;
    }
    __shared__ float red[256];
    red[tid] = s;
    __syncthreads();
    for (int off = 128; off > 0; off >>= 1) {
        if (tid < off) red[tid] += red[tid+off];
        __syncthreads();
    }
    if (tid == 0) x0[b*CC + i] = red[0];
}

// ---- spectral forward partials: A_c/A_s[b][i][k] over n-chunks ----
__global__ void __launch_bounds__(256) k_a(const float* __restrict__ xT,
                                           const float* __restrict__ nodes,
                                           const float* __restrict__ nwt,
                                           const float* __restrict__ modes,
                                           float* __restrict__ pc, float* __restrict__ ps) {
    int bc = blockIdx.x;
    int b = bc / PP, chunk = bc % PP;
    int tid = threadIdx.x;
    int lane = tid & 63;
    int w = tid >> 6;
    int khalf = w & 1;
    int ig = blockIdx.y*2 + (w >> 1);          // 0..3, 16 i's each
    int k = khalf*64 + lane;
    int i0 = __builtin_amdgcn_readfirstlane(ig * 16);
    float m0 = modes[k*3+0], m1 = modes[k*3+1], m2 = modes[k*3+2];
    float ac[16], as[16];
#pragma unroll
    for (int j = 0; j < 16; j++) { ac[j]=0.f; as[j]=0.f; }
    int nbase = chunk*LL;
    for (int t = 0; t < LL; t++) {
        int n = nbase + t;
        float nd0 = nodes[(b*NN+n)*3+0], nd1 = nodes[(b*NN+n)*3+1], nd2 = nodes[(b*NN+n)*3+2];
        float nw = nwt[b*NN+n];
        float tt = nd0*m0 + nd1*m1 + nd2*m2;
        float cv = __cosf(tt) * nw, sv = __sinf(tt) * nw;
        const float* __restrict__ xrow = &xT[((size_t)b*NN+n)*CC + i0];
#pragma unroll
        for (int j = 0; j < 16; j++) {
            float xv = xrow[j];
            ac[j] = fmaf(xv, cv, ac[j]);
            as[j] = fmaf(xv, sv, as[j]);
        }
    }
    int base = (b*PP + chunk)*CC;
#pragma unroll
    for (int j = 0; j < 16; j++) {
        pc[(size_t)(base + i0 + j)*KK + k] = ac[j];
        ps[(size_t)(base + i0 + j)*KK + k] = as[j];
    }
}

__global__ void k_ared(const float* __restrict__ pc, const float* __restrict__ ps,
                       float* __restrict__ Ac, float* __restrict__ As) {
    int idx = blockIdx.x*256 + threadIdx.x;      // over BB*CC*KK
    if (idx >= BB*CC*KK) return;
    int b = idx / (CC*KK);
    int r = idx % (CC*KK);
    float sc = 0.f, ss = 0.f;
    for (int ch = 0; ch < PP; ch++) {
        size_t o = ((size_t)(b*PP + ch)*CC)*KK + r;
        sc += pc[o]; ss += ps[o];
    }
    Ac[idx] = sc; As[idx] = ss;
}

// ---- channel mix -> 2*f_c, 2*f_s in [b][k][o] layout, + f0 ----
__global__ void k_b(const float* __restrict__ Ac, const float* __restrict__ As,
                    const float* __restrict__ wc, const float* __restrict__ wsw,
                    const float* __restrict__ w0, const float* __restrict__ x0,
                    float* __restrict__ fTc, float* __restrict__ fTs, float* __restrict__ f0) {
    int b = blockIdx.x / CC, o = blockIdx.x % CC;
    int k = threadIdx.x;                         // 128 threads
    float fc = 0.f, fs = 0.f;
    for (int i = 0; i < CC; i++) {
        float a_c = Ac[(b*CC+i)*KK + k];
        float a_s = As[(b*CC+i)*KK + k];
        float wcc = wc[((size_t)(i*CC+o))*KK + k];
        float wss = wsw[((size_t)(i*CC+o))*KK + k];
        fc += a_c*wcc + a_s*wss;
        fs += a_c*wss - a_s*wcc;
    }
    fTc[(b*KK+k)*CC + o] = 2.f*fc;
    fTs[(b*KK+k)*CC + o] = 2.f*fs;
    if (threadIdx.x == 0) {
        float acc = 0.f;
        for (int i = 0; i < CC; i++) acc += x0[b*CC+i]*w0[i*CC+o];
        f0[b*CC+o] = acc;
    }
}

// ---- edge binning ----
__global__ void k_count(const int* __restrict__ edges, int* __restrict__ counts) {
    int idx = blockIdx.x*256 + threadIdx.x;
    if (idx >= BB*EE) return;
    int tgt = edges[(size_t)idx*2 + 0];
    int b = idx / EE;
    atomicAdd(&counts[b*NN + tgt], 1);
}

__global__ void __launch_bounds__(1024) k_scan(const int* __restrict__ counts,
                                               int* __restrict__ offsets, int* __restrict__ cursor) {
    __shared__ int part[1024];
    int b = blockIdx.x;
    int tid = threadIdx.x;
    int base = tid*16;
    int loc[16]; int s = 0;
    for (int j = 0; j < 16; j++) { loc[j] = counts[b*NN + base + j]; s += loc[j]; }
    part[tid] = s;
    __syncthreads();
    for (int off = 1; off < 1024; off <<= 1) {
        int v = (tid >= off) ? part[tid-off] : 0;
        __syncthreads();
        part[tid] += v;
        __syncthreads();
    }
    int excl = part[tid] - s;
    for (int j = 0; j < 16; j++) {
        offsets[b*NN+base+j] = excl;
        cursor[b*NN+base+j]  = excl;
        excl += loc[j];
    }
}

__global__ void k_fill(const int* __restrict__ edges, int* __restrict__ cursor,
                       int2* __restrict__ binlist) {
    int idx = blockIdx.x*256 + threadIdx.x;
    if (idx >= BB*EE) return;
    int b = idx / EE, e = idx % EE;
    int tgt = edges[(size_t)idx*2+0];
    int src = edges[(size_t)idx*2+1];
    int pos = atomicAdd(&cursor[b*NN+tgt], 1);
    binlist[(size_t)b*EE + pos] = make_int2(src, e);
}

// ---- per-node edge accumulate -> gradfT[b][g][n] (atomics-free) ----
__global__ void __launch_bounds__(256) k_edge(const float* __restrict__ xT,
                                              const int* __restrict__ offsets,
                                              const int* __restrict__ counts,
                                              const int2* __restrict__ binlist,
                                              const float* __restrict__ egw,
                                              float* __restrict__ gradfT) {
    int blk = blockIdx.x;
    int b = blk / (NN/64);
    int n0 = (blk % (NN/64)) * 64;
    int tid = threadIdx.x;
    int lane = tid & 63;
    int w = tid >> 6;
    __shared__ float gl[64][193];    // [node_local][g], stride 193 -> 2-way banks
    for (int r = 0; r < 16; r++) {
        int nl = w*16 + r;
        int n = __builtin_amdgcn_readfirstlane(n0 + nl);
        float xtgt = xT[((size_t)b*NN+n)*CC + lane];
        float a0 = 0.f, a1 = 0.f, a2 = 0.f;
        int st  = offsets[b*NN+n];
        int cnt = counts[b*NN+n];
        for (int j = 0; j < cnt; j++) {
            int2 en = binlist[(size_t)b*EE + st + j];
            float xs = xT[((size_t)b*NN+en.x)*CC + lane];
            float d = xs - xtgt;
            const float* __restrict__ ew = &egw[((size_t)b*EE+en.y)*3];
            a0 = fmaf(d, ew[0], a0);
            a1 = fmaf(d, ew[1], a1);
            a2 = fmaf(d, ew[2], a2);
        }
        gl[nl][lane*3+0] = a0;
        gl[nl][lane*3+1] = a1;
        gl[nl][lane*3+2] = a2;
    }
    __syncthreads();
    for (int gg = 0; gg < 48; gg++) {
        int g = w*48 + gg;
        gradfT[((size_t)b*192+g)*NN + n0 + lane] = gl[lane][g];
    }
}

// ---- h[b][i][n] = softsign(geo_wx@geo) * (wx@x) ----
__global__ void __launch_bounds__(64) k_h(const float* __restrict__ x,
                                          const float* __restrict__ geo,
                                          const float* __restrict__ wxT,
                                          const float* __restrict__ gwxT,
                                          float* __restrict__ hbuf) {
    int blk = blockIdx.x;
    int b = blk / (NN/64);
    int n0 = (blk % (NN/64)) * 64;
    int i0 = blockIdx.y * 32;
    int lane = threadIdx.x;
    int n = n0 + lane;
    float xw[32];
#pragma unroll
    for (int ii = 0; ii < 32; ii++) xw[ii] = 0.f;
    for (int j = 0; j < CC; j++) {
        float xv = x[((size_t)b*CC+j)*NN + n];
        const float* __restrict__ wr = &wxT[j*CC + i0];
#pragma unroll
        for (int ii = 0; ii < 32; ii++) xw[ii] = fmaf(wr[ii], xv, xw[ii]);
    }
    float g0 = geo[((size_t)b*GG+0)*NN + n];
    float g1 = geo[((size_t)b*GG+1)*NN + n];
    float g2 = geo[((size_t)b*GG+2)*NN + n];
#pragma unroll
    for (int ii = 0; ii < 32; ii++) {
        int i = i0 + ii;
        float t = gwxT[0*CC+i]*g0 + gwxT[1*CC+i]*g1 + gwxT[2*CC+i]*g2;
        float ssv = t / (1.f + fabsf(t));
        hbuf[((size_t)b*CC+i)*NN + n] = ssv * xw[ii];
    }
}

// ---- fused final: x1 + x2 + x3 + x4 -> exact GELU ----
__global__ void __launch_bounds__(256) k_c(const float* __restrict__ x,
                                           const float* __restrict__ nodes,
                                           const float* __restrict__ modes,
                                           const float* __restrict__ fTc,
                                           const float* __restrict__ fTs,
                                           const float* __restrict__ f0,
                                           const float* __restrict__ WT,
                                           const float* __restrict__ w2T,
                                           const float* __restrict__ gwT,
                                           const float* __restrict__ gradfT,
                                           const float* __restrict__ hbuf,
                                           float* __restrict__ out) {
    int blk = blockIdx.x;
    int b = blk / (NN/64);
    int n0 = (blk % (NN/64)) * 64;
    int tid = threadIdx.x;
    int lane = tid & 63;
    int o0 = __builtin_amdgcn_readfirstlane((tid >> 6) * 16);
    int n = n0 + lane;
    __shared__ float csc[KK*64];     // [k][n]: bank = n%32 -> 2-way (free)
    __shared__ float css[KK*64];
    float nd0 = nodes[((size_t)b*NN+n)*3+0];
    float nd1 = nodes[((size_t)b*NN+n)*3+1];
    float nd2 = nodes[((size_t)b*NN+n)*3+2];
    for (int r = 0; r < 32; r++) {
        int k = __builtin_amdgcn_readfirstlane(r*4 + (tid >> 6));
        float t = nd0*modes[k*3+0] + nd1*modes[k*3+1] + nd2*modes[k*3+2];
        csc[k*64+lane] = __cosf(t);
        css[k*64+lane] = __sinf(t);
    }
    __syncthreads();
    float acc[16];
    const float* __restrict__ f0p = &f0[b*CC + o0];
#pragma unroll
    for (int oo = 0; oo < 16; oo++) acc[oo] = f0p[oo];
    for (int k = 0; k < KK; k++) {
        float cv = csc[k*64 + lane];
        float sv = css[k*64 + lane];
        const float* __restrict__ fc = &fTc[(b*KK+k)*CC + o0];
        const float* __restrict__ fs = &fTs[(b*KK+k)*CC + o0];
#pragma unroll
        for (int oo = 0; oo < 16; oo++)
            acc[oo] += fc[oo]*cv - fs[oo]*sv;
    }
    for (int j = 0; j < CC; j++) {
        float xv = x[((size_t)b*CC+j)*NN + n];
        const float* __restrict__ wr = &WT[j*CC + o0];
#pragma unroll
        for (int oo = 0; oo < 16; oo++) acc[oo] = fmaf(wr[oo], xv, acc[oo]);
    }
    for (int i = 0; i < CC; i++) {
        float hv = hbuf[((size_t)b*CC+i)*NN + n];
        const float* __restrict__ wr = &w2T[i*CC + o0];
#pragma unroll
        for (int oo = 0; oo < 16; oo++) acc[oo] = fmaf(wr[oo], hv, acc[oo]);
    }
    for (int g = 0; g < 192; g++) {
        float gv = gradfT[((size_t)b*192+g)*NN + n];
        const float* __restrict__ wr = &gwT[g*CC + o0];
#pragma unroll
        for (int oo = 0; oo < 16; oo++) acc[oo] = fmaf(wr[oo], gv, acc[oo]);
    }
#pragma unroll
    for (int oo = 0; oo < 16; oo++) {
        float v = acc[oo];
        float r = 0.5f * v * (1.f + erff(v * 0.70710678118654752f));
        out[((size_t)b*CC + o0 + oo)*NN + n] = r;
    }
}

extern "C" void kernel_launch(void* const* d_in, const int* in_sizes, int n_in,
                              void* d_out, int out_size, void* d_ws, size_t ws_size,
                              hipStream_t stream) {
    const float* x      = (const float*)d_in[0];
    const float* nodes  = (const float*)d_in[1];
    const float* nwt    = (const float*)d_in[2];
    const float* geo    = (const float*)d_in[3];
    const int*   edges  = (const int*)d_in[4];
    const float* egw    = (const float*)d_in[5];
    const float* modes  = (const float*)d_in[6];
    const float* wc     = (const float*)d_in[7];
    const float* wsw    = (const float*)d_in[8];
    const float* w0     = (const float*)d_in[9];
    const float* W      = (const float*)d_in[10];
    const float* gw     = (const float*)d_in[11];
    const float* geo_wx = (const float*)d_in[12];
    const float* wx     = (const float*)d_in[13];
    const float* w2     = (const float*)d_in[14];

    float* ws   = (float*)d_ws;
    float* xT   = ws + OFF_XT;
    float* pc   = ws + OFF_PC;
    float* ps   = ws + OFF_PS;
    float* Ac   = ws + OFF_AC;
    float* As   = ws + OFF_AS;
    float* fTc  = ws + OFF_FTC;
    float* fTs  = ws + OFF_FTS;
    float* f0   = ws + OFF_F0;
    float* x0   = ws + OFF_X0;
    int*  counts = (int*)(ws + OFF_CNT);
    int*  offs   = (int*)(ws + OFF_OFFS);
    int*  cur    = (int*)(ws + OFF_CUR);
    int2* bin    = (int2*)(ws + OFF_BIN);
    float* gradfT = ws + OFF_GRT;
    float* hbuf   = ws + OFF_H;
    float* WT   = ws + OFF_WT;
    float* wxT  = ws + OFF_WXT;
    float* w2T  = ws + OFF_W2T;
    float* gwT  = ws + OFF_GWT;
    float* gwxT = ws + OFF_GWXT;
    float* out  = (float*)d_out;

    hipMemsetAsync(counts, 0, (size_t)(BB*NN)*sizeof(int), stream);

    k_prep <<<48, 256, 0, stream>>>(W, gw, geo_wx, wx, w2, WT, wxT, w2T, gwT, gwxT);
    k_xt   <<<BB*(NN/64), 256, 0, stream>>>(x, xT);
    k_x0   <<<BB*CC, 256, 0, stream>>>(x, nwt, x0);
    k_a    <<<dim3(BB*PP, 2), 256, 0, stream>>>(xT, nodes, nwt, modes, pc, ps);
    k_ared <<<(BB*CC*KK)/256, 256, 0, stream>>>(pc, ps, Ac, As);
    k_b    <<<BB*CC, 128, 0, stream>>>(Ac, As, wc, wsw, w0, x0, fTc, fTs, f0);
    k_count<<<(BB*EE)/256, 256, 0, stream>>>(edges, counts);
    k_scan <<<BB, 1024, 0, stream>>>(counts, offs, cur);
    k_fill <<<(BB*EE)/256, 256, 0, stream>>>(edges, cur, bin);
    k_edge <<<BB*(NN/64), 256, 0, stream>>>(xT, offs, counts, bin, egw, gradfT);
    k_h    <<<dim3(BB*(NN/64), 2), 64, 0, stream>>>(x, geo, wxT, gwxT, hbuf);
    k_c    <<<BB*(NN/64), 256, 0, stream>>>(x, nodes, modes, fTc, fTs, f0, WT, w2T, gwT,
                                            gradfT, hbuf, out);
}

// Round 3
// 415.098 us; speedup vs baseline: 2.2069x; 1.1755x over previous
//
#include <hip/hip_runtime.h>
#include <math.h>

#define BB 2
#define CC 64
#define NN 16384
#define DD 3
#define KK 128
#define EE 262144
#define GG 3
#define PP 64            // n-chunks for spectral-forward partials
#define LL (NN/PP)       // 256 n per chunk

// ---- workspace layout (float elements) ----
constexpr size_t OFF_XT   = 0;                                  // xT[b][n][i]
constexpr size_t OFF_PC   = OFF_XT   + (size_t)BB*NN*CC;        // partial A_c
constexpr size_t OFF_PS   = OFF_PC   + (size_t)BB*PP*CC*KK;     // partial A_s
// bin4 aliases pc/ps (pc/ps dead after k_ared; k_fill runs later in-stream)
constexpr size_t OFF_BIN4 = OFF_PC;                             // float4 binlist[b][E]
constexpr size_t OFF_AC   = OFF_PS   + (size_t)BB*PP*CC*KK;     // A_c[b][i][k]
constexpr size_t OFF_AS   = OFF_AC   + (size_t)BB*CC*KK;
constexpr size_t OFF_FTC  = OFF_AS   + (size_t)BB*CC*KK;        // 2*f_c[b][k][o]
constexpr size_t OFF_FTS  = OFF_FTC  + (size_t)BB*KK*CC;        // 2*f_s[b][k][o]
constexpr size_t OFF_F0   = OFF_FTS  + (size_t)BB*KK*CC;        // f0[b][o]
constexpr size_t OFF_X0   = OFF_F0   + (size_t)BB*CC;           // x0[b][i]
constexpr size_t OFF_CNT  = OFF_X0   + (size_t)BB*CC;           // int counts (zeroed)
constexpr size_t OFF_OFFS = OFF_CNT  + (size_t)BB*NN;           // int offsets
constexpr size_t OFF_CUR  = OFF_OFFS + (size_t)BB*NN;           // int cursor
constexpr size_t OFF_GRT  = OFF_CUR  + (size_t)BB*NN;           // gradfT[b][g][n]
constexpr size_t OFF_H    = OFF_GRT  + (size_t)BB*192*NN;       // h[b][i][n]
constexpr size_t OFF_WT   = OFF_H    + (size_t)BB*CC*NN;        // W^T  [j][o]
constexpr size_t OFF_WXT  = OFF_WT   + (size_t)CC*CC;           // wx^T [j][i]
constexpr size_t OFF_W2T  = OFF_WXT  + (size_t)CC*CC;           // w2^T [i][o]
constexpr size_t OFF_GWT  = OFF_W2T  + (size_t)CC*CC;           // gw^T [g][o]
constexpr size_t OFF_GWXT = OFF_GWT  + (size_t)CC*CC*DD;        // geo_wx^T [g][i]

// ---- small transposes ----
__global__ void k_prep(const float* __restrict__ W, const float* __restrict__ gw,
                       const float* __restrict__ geo_wx, const float* __restrict__ wx,
                       const float* __restrict__ w2,
                       float* WT, float* wxT, float* w2T, float* gwT, float* gwxT) {
    int idx = blockIdx.x*256 + threadIdx.x;
    if (idx < CC*CC) { int j = idx>>6, o = idx&63; WT[idx]  = W[o*CC+j];  }
    if (idx < CC*CC) { int j = idx>>6, i = idx&63; wxT[idx] = wx[i*CC+j]; }
    if (idx < CC*CC) { int i = idx>>6, o = idx&63; w2T[idx] = w2[o*CC+i]; }
    if (idx < CC*CC*DD) { int g = idx>>6, o = idx&63; gwT[idx] = gw[o*(CC*DD)+g]; }
    if (idx < GG*CC) { int g = idx>>6, i = idx&63; gwxT[idx] = geo_wx[i*GG+g]; }
}

// ---- transpose x -> xT[b][n][i] ----
__global__ void __launch_bounds__(256) k_xt(const float* __restrict__ x,
                                            float* __restrict__ xT) {
    int blk = blockIdx.x;
    int b = blk / (NN/64);
    int n0 = (blk % (NN/64)) * 64;
    __shared__ float tile[64][65];
    int tid = threadIdx.x;
    int c = tid & 63, r4 = tid >> 6;
    for (int rr = 0; rr < 16; rr++) {
        int i = r4*16 + rr;
        tile[i][c] = x[((size_t)b*CC + i)*NN + n0 + c];
    }
    __syncthreads();
    for (int rr = 0; rr < 16; rr++) {
        int nn = r4*16 + rr;
        xT[((size_t)b*NN + n0 + nn)*CC + c] = tile[c][nn];
    }
}

// ---- x0[b][i] = sum_n x[b,i,n] * nw[b,n] ----
__global__ void __launch_bounds__(256) k_x0(const float* __restrict__ x,
                                            const float* __restrict__ nwt,
                                            float* __restrict__ x0) {
    int b = blockIdx.x >> 6;
    int i = blockIdx.x & 63;
    int tid = threadIdx.x;
    const float4* __restrict__ xr = (const float4*)&x[((size_t)b*CC + i)*NN];
    const float4* __restrict__ wr = (const float4*)&nwt[(size_t)b*NN];
    float s = 0.f;
    for (int t = tid; t < NN/4; t += 256) {
        float4 xv = xr[t];
        float4 wv = wr[t];
        s += xv.x*wv.x + xv.y*wv.y + xv.z*wv.z + xv.w*wv.w;
    }
    __shared__ float red[256];
    red[tid] = s;
    __syncthreads();
    for (int off = 128; off > 0; off >>= 1) {
        if (tid < off) red[tid] += red[tid+off];
        __syncthreads();
    }
    if (tid == 0) x0[b*CC + i] = red[0];
}

// ---- spectral forward partials: A_c/A_s[b][i][k] over n-chunks ----
__global__ void __launch_bounds__(256) k_a(const float* __restrict__ xT,
                                           const float* __restrict__ nodes,
                                           const float* __restrict__ nwt,
                                           const float* __restrict__ modes,
                                           float* __restrict__ pc, float* __restrict__ ps) {
    int bc = blockIdx.x;
    int b = bc / PP, chunk = bc % PP;
    int tid = threadIdx.x;
    int lane = tid & 63;
    int w = tid >> 6;
    int khalf = w & 1;
    int ig = blockIdx.y*2 + (w >> 1);
    int k = khalf*64 + lane;
    int i0 = __builtin_amdgcn_readfirstlane(ig * 16);
    float m0 = modes[k*3+0], m1 = modes[k*3+1], m2 = modes[k*3+2];
    float ac[16], as[16];
#pragma unroll
    for (int j = 0; j < 16; j++) { ac[j]=0.f; as[j]=0.f; }
    int nbase = chunk*LL;
    for (int t = 0; t < LL; t++) {
        int n = nbase + t;
        float nd0 = nodes[(b*NN+n)*3+0], nd1 = nodes[(b*NN+n)*3+1], nd2 = nodes[(b*NN+n)*3+2];
        float nw = nwt[b*NN+n];
        float tt = nd0*m0 + nd1*m1 + nd2*m2;
        float cv = __cosf(tt) * nw, sv = __sinf(tt) * nw;
        const float* __restrict__ xrow = &xT[((size_t)b*NN+n)*CC + i0];
#pragma unroll
        for (int j = 0; j < 16; j++) {
            float xv = xrow[j];
            ac[j] = fmaf(xv, cv, ac[j]);
            as[j] = fmaf(xv, sv, as[j]);
        }
    }
    int base = (b*PP + chunk)*CC;
#pragma unroll
    for (int j = 0; j < 16; j++) {
        pc[(size_t)(base + i0 + j)*KK + k] = ac[j];
        ps[(size_t)(base + i0 + j)*KK + k] = as[j];
    }
}

__global__ void k_ared(const float* __restrict__ pc, const float* __restrict__ ps,
                       float* __restrict__ Ac, float* __restrict__ As) {
    int idx = blockIdx.x*256 + threadIdx.x;
    if (idx >= BB*CC*KK) return;
    int b = idx / (CC*KK);
    int r = idx % (CC*KK);
    float sc = 0.f, ss = 0.f;
    for (int ch = 0; ch < PP; ch++) {
        size_t o = ((size_t)(b*PP + ch)*CC)*KK + r;
        sc += pc[o]; ss += ps[o];
    }
    Ac[idx] = sc; As[idx] = ss;
}

// ---- channel mix -> 2*f_c, 2*f_s in [b][k][o] layout, + f0 ----
__global__ void k_b(const float* __restrict__ Ac, const float* __restrict__ As,
                    const float* __restrict__ wc, const float* __restrict__ wsw,
                    const float* __restrict__ w0, const float* __restrict__ x0,
                    float* __restrict__ fTc, float* __restrict__ fTs, float* __restrict__ f0) {
    int b = blockIdx.x / CC, o = blockIdx.x % CC;
    int k = threadIdx.x;
    float fc = 0.f, fs = 0.f;
    for (int i = 0; i < CC; i++) {
        float a_c = Ac[(b*CC+i)*KK + k];
        float a_s = As[(b*CC+i)*KK + k];
        float wcc = wc[((size_t)(i*CC+o))*KK + k];
        float wss = wsw[((size_t)(i*CC+o))*KK + k];
        fc += a_c*wcc + a_s*wss;
        fs += a_c*wss - a_s*wcc;
    }
    fTc[(b*KK+k)*CC + o] = 2.f*fc;
    fTs[(b*KK+k)*CC + o] = 2.f*fs;
    if (threadIdx.x == 0) {
        float acc = 0.f;
        for (int i = 0; i < CC; i++) acc += x0[b*CC+i]*w0[i*CC+o];
        f0[b*CC+o] = acc;
    }
}

// ---- edge binning ----
__global__ void k_count(const int* __restrict__ edges, int* __restrict__ counts) {
    int idx = blockIdx.x*256 + threadIdx.x;
    if (idx >= BB*EE) return;
    int tgt = edges[(size_t)idx*2 + 0];
    int b = idx / EE;
    atomicAdd(&counts[b*NN + tgt], 1);
}

__global__ void __launch_bounds__(1024) k_scan(const int* __restrict__ counts,
                                               int* __restrict__ offsets, int* __restrict__ cursor) {
    __shared__ int part[1024];
    int b = blockIdx.x;
    int tid = threadIdx.x;
    int base = tid*16;
    int loc[16]; int s = 0;
    for (int j = 0; j < 16; j++) { loc[j] = counts[b*NN + base + j]; s += loc[j]; }
    part[tid] = s;
    __syncthreads();
    for (int off = 1; off < 1024; off <<= 1) {
        int v = (tid >= off) ? part[tid-off] : 0;
        __syncthreads();
        part[tid] += v;
        __syncthreads();
    }
    int excl = part[tid] - s;
    for (int j = 0; j < 16; j++) {
        offsets[b*NN+base+j] = excl;
        cursor[b*NN+base+j]  = excl;
        excl += loc[j];
    }
}

// ---- fill bins with packed {src, w0, w1, w2} entries ----
__global__ void k_fill(const int* __restrict__ edges, const float* __restrict__ egw,
                       int* __restrict__ cursor, float4* __restrict__ bin4) {
    int idx = blockIdx.x*256 + threadIdx.x;
    if (idx >= BB*EE) return;
    int b = idx / EE, e = idx % EE;
    int tgt = edges[(size_t)idx*2+0];
    int src = edges[(size_t)idx*2+1];
    const float* __restrict__ ew = &egw[(size_t)idx*3];
    float w0 = ew[0], w1 = ew[1], w2 = ew[2];
    int pos = atomicAdd(&cursor[b*NN+tgt], 1);
    bin4[(size_t)b*EE + pos] = make_float4(__int_as_float(src), w0, w1, w2);
    (void)e;
}

// ---- per-node edge accumulate -> gradfT[b][g][n] ----
// 16-node tiles, LDS-staged edge entries, xtgt hoisted out of the edge loop:
// grad[n] = sum_e x[src_e]*w_e  -  x[n] * sum_e w_e
#define ECAP 1024
__global__ void __launch_bounds__(256) k_edge(const float* __restrict__ xT,
                                              const int* __restrict__ offsets,
                                              const float4* __restrict__ bin4,
                                              float* __restrict__ gradfT) {
    int blk = blockIdx.x;
    int b = blk / (NN/16);
    int n0 = (blk % (NN/16)) * 16;
    int tid = threadIdx.x;
    int lane = tid & 63;
    int w = tid >> 6;                 // 4 waves, 4 nodes each
    __shared__ float4 ebuf[ECAP];
    __shared__ float gl[16][193];
    __shared__ int soff[17];
    if (tid < 16) soff[tid] = offsets[b*NN + n0 + tid];
    if (tid == 16) soff[16] = (n0 + 16 < NN) ? offsets[b*NN + n0 + 16] : EE;
    __syncthreads();
    int base = soff[0];
    int end  = soff[16];
    const float* __restrict__ xTb = &xT[(size_t)b*NN*CC + lane];

    float a0[4], a1[4], a2[4], s0[4], s1[4], s2[4];
#pragma unroll
    for (int q = 0; q < 4; q++) { a0[q]=a1[q]=a2[q]=0.f; s0[q]=s1[q]=s2[q]=0.f; }

    for (int cs = base; cs < end; cs += ECAP) {
        int ce = min(cs + ECAP, end);
        __syncthreads();
        for (int t = cs + tid; t < ce; t += 256)
            ebuf[t - cs] = bin4[(size_t)b*EE + t];
        __syncthreads();
#pragma unroll
        for (int q = 0; q < 4; q++) {
            int nl = w*4 + q;
            int js = max(soff[nl], cs);
            int je = min(soff[nl+1], ce);
#pragma unroll 2
            for (int j = js; j < je; j++) {
                float4 e = ebuf[j - cs];
                int src = __float_as_int(e.x);
                float xs = xTb[(size_t)src*CC];
                a0[q] = fmaf(xs, e.y, a0[q]);
                a1[q] = fmaf(xs, e.z, a1[q]);
                a2[q] = fmaf(xs, e.w, a2[q]);
                s0[q] += e.y; s1[q] += e.z; s2[q] += e.w;
            }
        }
    }
    __syncthreads();
#pragma unroll
    for (int q = 0; q < 4; q++) {
        int nl = w*4 + q;
        float xtgt = xTb[(size_t)(n0 + nl)*CC];
        gl[nl][lane*3+0] = a0[q] - xtgt*s0[q];
        gl[nl][lane*3+1] = a1[q] - xtgt*s1[q];
        gl[nl][lane*3+2] = a2[q] - xtgt*s2[q];
    }
    __syncthreads();
    for (int t = tid; t < 16*192; t += 256) {
        int g = t >> 4, nl = t & 15;
        gradfT[((size_t)b*192+g)*NN + n0 + nl] = gl[nl][g];
    }
}

// ---- h[b][i][n] = softsign(geo_wx@geo) * (wx@x) ----
__global__ void __launch_bounds__(64) k_h(const float* __restrict__ x,
                                          const float* __restrict__ geo,
                                          const float* __restrict__ wxT,
                                          const float* __restrict__ gwxT,
                                          float* __restrict__ hbuf) {
    int blk = blockIdx.x;
    int b = blk / (NN/64);
    int n0 = (blk % (NN/64)) * 64;
    int i0 = blockIdx.y * 32;
    int lane = threadIdx.x;
    int n = n0 + lane;
    float xw[32];
#pragma unroll
    for (int ii = 0; ii < 32; ii++) xw[ii] = 0.f;
    for (int j = 0; j < CC; j++) {
        float xv = x[((size_t)b*CC+j)*NN + n];
        const float* __restrict__ wr = &wxT[j*CC + i0];
#pragma unroll
        for (int ii = 0; ii < 32; ii++) xw[ii] = fmaf(wr[ii], xv, xw[ii]);
    }
    float g0 = geo[((size_t)b*GG+0)*NN + n];
    float g1 = geo[((size_t)b*GG+1)*NN + n];
    float g2 = geo[((size_t)b*GG+2)*NN + n];
#pragma unroll
    for (int ii = 0; ii < 32; ii++) {
        int i = i0 + ii;
        float t = gwxT[0*CC+i]*g0 + gwxT[1*CC+i]*g1 + gwxT[2*CC+i]*g2;
        float ssv = t / (1.f + fabsf(t));
        hbuf[((size_t)b*CC+i)*NN + n] = ssv * xw[ii];
    }
}

// ---- fused final: x1 + x2 + x3 + x4 -> exact GELU ----
__global__ void __launch_bounds__(256) k_c(const float* __restrict__ x,
                                           const float* __restrict__ nodes,
                                           const float* __restrict__ modes,
                                           const float* __restrict__ fTc,
                                           const float* __restrict__ fTs,
                                           const float* __restrict__ f0,
                                           const float* __restrict__ WT,
                                           const float* __restrict__ w2T,
                                           const float* __restrict__ gwT,
                                           const float* __restrict__ gradfT,
                                           const float* __restrict__ hbuf,
                                           float* __restrict__ out) {
    int blk = blockIdx.x;
    int b = blk / (NN/64);
    int n0 = (blk % (NN/64)) * 64;
    int tid = threadIdx.x;
    int lane = tid & 63;
    int o0 = __builtin_amdgcn_readfirstlane((tid >> 6) * 16);
    int n = n0 + lane;
    __shared__ float csc[KK*64];
    __shared__ float css[KK*64];
    float nd0 = nodes[((size_t)b*NN+n)*3+0];
    float nd1 = nodes[((size_t)b*NN+n)*3+1];
    float nd2 = nodes[((size_t)b*NN+n)*3+2];
    for (int r = 0; r < 32; r++) {
        int k = __builtin_amdgcn_readfirstlane(r*4 + (tid >> 6));
        float t = nd0*modes[k*3+0] + nd1*modes[k*3+1] + nd2*modes[k*3+2];
        csc[k*64+lane] = __cosf(t);
        css[k*64+lane] = __sinf(t);
    }
    __syncthreads();
    float acc[16];
    const float* __restrict__ f0p = &f0[b*CC + o0];
#pragma unroll
    for (int oo = 0; oo < 16; oo++) acc[oo] = f0p[oo];
    for (int k = 0; k < KK; k++) {
        float cv = csc[k*64 + lane];
        float sv = css[k*64 + lane];
        const float* __restrict__ fc = &fTc[(b*KK+k)*CC + o0];
        const float* __restrict__ fs = &fTs[(b*KK+k)*CC + o0];
#pragma unroll
        for (int oo = 0; oo < 16; oo++)
            acc[oo] += fc[oo]*cv - fs[oo]*sv;
    }
    for (int j = 0; j < CC; j++) {
        float xv = x[((size_t)b*CC+j)*NN + n];
        const float* __restrict__ wr = &WT[j*CC + o0];
#pragma unroll
        for (int oo = 0; oo < 16; oo++) acc[oo] = fmaf(wr[oo], xv, acc[oo]);
    }
    for (int i = 0; i < CC; i++) {
        float hv = hbuf[((size_t)b*CC+i)*NN + n];
        const float* __restrict__ wr = &w2T[i*CC + o0];
#pragma unroll
        for (int oo = 0; oo < 16; oo++) acc[oo] = fmaf(wr[oo], hv, acc[oo]);
    }
    for (int g = 0; g < 192; g++) {
        float gv = gradfT[((size_t)b*192+g)*NN + n];
        const float* __restrict__ wr = &gwT[g*CC + o0];
#pragma unroll
        for (int oo = 0; oo < 16; oo++) acc[oo] = fmaf(wr[oo], gv, acc[oo]);
    }
#pragma unroll
    for (int oo = 0; oo < 16; oo++) {
        float v = acc[oo];
        float r = 0.5f * v * (1.f + erff(v * 0.70710678118654752f));
        out[((size_t)b*CC + o0 + oo)*NN + n] = r;
    }
}

extern "C" void kernel_launch(void* const* d_in, const int* in_sizes, int n_in,
                              void* d_out, int out_size, void* d_ws, size_t ws_size,
                              hipStream_t stream) {
    const float* x      = (const float*)d_in[0];
    const float* nodes  = (const float*)d_in[1];
    const float* nwt    = (const float*)d_in[2];
    const float* geo    = (const float*)d_in[3];
    const int*   edges  = (const int*)d_in[4];
    const float* egw    = (const float*)d_in[5];
    const float* modes  = (const float*)d_in[6];
    const float* wc     = (const float*)d_in[7];
    const float* wsw    = (const float*)d_in[8];
    const float* w0     = (const float*)d_in[9];
    const float* W      = (const float*)d_in[10];
    const float* gw     = (const float*)d_in[11];
    const float* geo_wx = (const float*)d_in[12];
    const float* wx     = (const float*)d_in[13];
    const float* w2     = (const float*)d_in[14];

    float* ws   = (float*)d_ws;
    float* xT   = ws + OFF_XT;
    float* pc   = ws + OFF_PC;
    float* ps   = ws + OFF_PS;
    float* Ac   = ws + OFF_AC;
    float* As   = ws + OFF_AS;
    float* fTc  = ws + OFF_FTC;
    float* fTs  = ws + OFF_FTS;
    float* f0   = ws + OFF_F0;
    float* x0   = ws + OFF_X0;
    int*  counts = (int*)(ws + OFF_CNT);
    int*  offs   = (int*)(ws + OFF_OFFS);
    int*  cur    = (int*)(ws + OFF_CUR);
    float4* bin4 = (float4*)(ws + OFF_BIN4);
    float* gradfT = ws + OFF_GRT;
    float* hbuf   = ws + OFF_H;
    float* WT   = ws + OFF_WT;
    float* wxT  = ws + OFF_WXT;
    float* w2T  = ws + OFF_W2T;
    float* gwT  = ws + OFF_GWT;
    float* gwxT = ws + OFF_GWXT;
    float* out  = (float*)d_out;

    hipMemsetAsync(counts, 0, (size_t)(BB*NN)*sizeof(int), stream);

    k_prep <<<48, 256, 0, stream>>>(W, gw, geo_wx, wx, w2, WT, wxT, w2T, gwT, gwxT);
    k_xt   <<<BB*(NN/64), 256, 0, stream>>>(x, xT);
    k_x0   <<<BB*CC, 256, 0, stream>>>(x, nwt, x0);
    k_a    <<<dim3(BB*PP, 2), 256, 0, stream>>>(xT, nodes, nwt, modes, pc, ps);
    k_ared <<<(BB*CC*KK)/256, 256, 0, stream>>>(pc, ps, Ac, As);
    k_b    <<<BB*CC, 128, 0, stream>>>(Ac, As, wc, wsw, w0, x0, fTc, fTs, f0);
    k_count<<<(BB*EE)/256, 256, 0, stream>>>(edges, counts);
    k_scan <<<BB, 1024, 0, stream>>>(counts, offs, cur);
    k_fill <<<(BB*EE)/256, 256, 0, stream>>>(edges, egw, cur, bin4);
    k_edge <<<BB*(NN/16), 256, 0, stream>>>(xT, offs, bin4, gradfT);
    k_h    <<<dim3(BB*(NN/64), 2), 64, 0, stream>>>(x, geo, wxT, gwxT, hbuf);
    k_c    <<<BB*(NN/64), 256, 0, stream>>>(x, nodes, modes, fTc, fTs, f0, WT, w2T, gwT,
                                            gradfT, hbuf, out);
}